// Round 4
// baseline (222.814 us; speedup 1.0000x reference)
//
#include <hip/hip_runtime.h>
#include <hip/hip_bf16.h>
#include <cstdint>
#include <cstddef>

// ---- problem constants ----
#define NIN   2048
#define RANK  64
#define R2    128      // 2*RANK
#define NROWS 16384    // 8*2048 flattened batch*seq rows

typedef __bf16 bf16x8 __attribute__((ext_vector_type(8)));
typedef float  f32x4  __attribute__((ext_vector_type(4)));
typedef unsigned short u16x8 __attribute__((ext_vector_type(8)));

__device__ __forceinline__ unsigned short f2bf(float f) {
  union { float f; unsigned u; } x; x.f = f;
  return (unsigned short)((x.u + 0x7fffu + ((x.u >> 16) & 1u)) >> 16);
}

// ---- 1) MbfT[n][k] = bf16(M[k][n]) via LDS transpose; also zero G ----
// 64 blocks x 256 threads; block = 32 k-rows x 128 n-cols.
__global__ void k_convM(const float* __restrict__ U, const float* __restrict__ V,
                        unsigned short* __restrict__ MbfT, float* __restrict__ G) {
  __shared__ unsigned short lds[32][130];
  int gidx = blockIdx.x * 256 + threadIdx.x;       // 16384 threads == R2*R2
  G[gidx] = 0.f;
  int k0 = blockIdx.x * 32;
  int tn = threadIdx.x & 127, tk2 = threadIdx.x >> 7;   // tk2 in {0,1}
  const float* src = (tn < RANK) ? (U + tn) : (V + (tn - RANK));
#pragma unroll
  for (int i = 0; i < 16; ++i) {
    int kk = tk2 * 16 + i;
    lds[kk][tn] = f2bf(src[(size_t)(k0 + kk) * RANK]);  // coalesced 256B per kk
  }
  __syncthreads();
  int n = threadIdx.x >> 1, kg = threadIdx.x & 1;
  u16x8 o1, o2;
#pragma unroll
  for (int j = 0; j < 8; ++j) { o1[j] = lds[kg * 16 + j][n]; o2[j] = lds[kg * 16 + 8 + j][n]; }
  unsigned short* dst = MbfT + (size_t)n * NIN + k0 + kg * 16;
  *(u16x8*)dst = o1;
  *(u16x8*)(dst + 8) = o2;
}

// ---- 2) G = J * (M^T M), fp32, K split 8 ways + atomicAdd ----
__global__ void k_SG(const float* __restrict__ U, const float* __restrict__ V,
                     float* __restrict__ G) {
  int b = blockIdx.x;                  // 512 blocks = 64 tiles x 8 ksplits
  int tile = b >> 3, ks = b & 7;
  int bi = tile >> 3, bj = tile & 7;
  int ty = threadIdx.x >> 4, tx = threadIdx.x & 15;
  int i = bi * 16 + ty, j = bj * 16 + tx;
  const float* Ai = (i < RANK) ? (U + i) : (V + (i - RANK));
  const float* Aj = (j < RANK) ? (U + j) : (V + (j - RANK));
  int k0 = ks * 256;
  float acc = 0.f;
#pragma unroll 8
  for (int k = k0; k < k0 + 256; ++k) acc += Ai[(size_t)k * RANK] * Aj[(size_t)k * RANK];
  if (i < RANK) atomicAdd(&G[(i + RANK) * R2 + j], -acc);
  else          atomicAdd(&G[(i - RANK) * R2 + j],  acc);
}

// ---- 3) generic small 128x128 GEMM: O = (A + a*I)(B + b*I), fp32 ----
struct SOp { const float* A; const float* B; float* O; float a, b; };
struct SOps { SOp op[3]; };
__global__ void k_small(SOps ops) {
  SOp o = ops.op[blockIdx.x >> 6];     // 64 blocks per op
  int t = blockIdx.x & 63;
  int i = (t >> 3) * 16 + (threadIdx.x >> 4);
  int j = (t & 7) * 16 + (threadIdx.x & 15);
  float acc = 0.f;
#pragma unroll 8
  for (int k = 0; k < R2; ++k) {
    float av = o.A[i * R2 + k]; if (k == i) av += o.a;
    float bv = o.B[k * R2 + j]; if (k == j) bv += o.b;
    acc += av * bv;
  }
  o.O[i * R2 + j] = acc;
}

// ---- 4) Dbf = bf16( M * ((2H - G15) * J) ),  2048x128 row-major ----
__global__ void k_D(const float* __restrict__ U, const float* __restrict__ V,
                    const float* __restrict__ H, const float* __restrict__ G15,
                    unsigned short* __restrict__ Dbf) {
  int idx = blockIdx.x * 256 + threadIdx.x;  // i*128 + j, i < 2048
  int i = idx >> 7, j = idx & 127;
  int jj = (j < RANK) ? (j + RANK) : (j - RANK);
  float sgn = (j < RANK) ? -1.f : 1.f;
  float acc = 0.f;
#pragma unroll 8
  for (int k = 0; k < R2; ++k) {
    float m = (k < RANK) ? U[(size_t)i * RANK + k] : V[(size_t)i * RANK + (k - RANK)];
    float t = 2.f * H[k * R2 + jj] - G15[k * R2 + jj];
    acc += m * (sgn * t);
  }
  Dbf[idx] = f2bf(acc);
}

// ---- 5) T1bf = bf16(input @ M), K split across waves, 2-deep SW pipeline ----
// grid 1024 blocks x 256 threads. Block = 16 rows. Wave w: K in [w*512,(w+1)*512).
__global__ __launch_bounds__(256) void k_T1(const float* __restrict__ input,
                                            const unsigned short* __restrict__ MbfT,
                                            unsigned short* __restrict__ T1bf) {
  __shared__ float buf[4][128][18];
  const int tid = threadIdx.x, lane = tid & 63, w = tid >> 6;
  const int lr = lane & 15, lg = lane >> 4;
  const int row0 = blockIdx.x * 16;

  f32x4 acc1[8] = {};
  const float* arow = input + (size_t)(row0 + lr) * NIN + w * 512 + lg * 8;
  const unsigned short* bbase = MbfT + (size_t)lr * NIN + w * 512 + lg * 8;

  float4 xa0, xa1, ya0, ya1;
  bf16x8 xb[8], yb[8];

#define T1_LOAD(P, KT)                                                        \
  do {                                                                        \
    P##a0 = *(const float4*)(arow + (KT) * 32);                               \
    P##a1 = *(const float4*)(arow + (KT) * 32 + 4);                           \
    _Pragma("unroll")                                                         \
    for (int n = 0; n < 8; ++n)                                               \
      P##b[n] = *(const bf16x8*)(bbase + (KT) * 32 + (size_t)n * 16 * NIN);   \
  } while (0)

#define T1_COMP(P)                                                            \
  do {                                                                        \
    bf16x8 af;                                                                \
    af[0] = (__bf16)P##a0.x; af[1] = (__bf16)P##a0.y;                         \
    af[2] = (__bf16)P##a0.z; af[3] = (__bf16)P##a0.w;                         \
    af[4] = (__bf16)P##a1.x; af[5] = (__bf16)P##a1.y;                         \
    af[6] = (__bf16)P##a1.z; af[7] = (__bf16)P##a1.w;                         \
    _Pragma("unroll")                                                         \
    for (int n = 0; n < 8; ++n)                                               \
      acc1[n] = __builtin_amdgcn_mfma_f32_16x16x32_bf16(af, P##b[n], acc1[n], 0, 0, 0); \
  } while (0)

  T1_LOAD(x, 0);
  for (int kt = 0; kt < 16; kt += 2) {
    T1_LOAD(y, kt + 1);
    T1_COMP(x);
    if (kt + 2 < 16) T1_LOAD(x, kt + 2);
    T1_COMP(y);
  }

  // partials -> LDS: C layout col = n*16+lr, row = lg*4+r  (store [col][row])
#pragma unroll
  for (int n = 0; n < 8; ++n) {
    int col = n * 16 + lr;
    float2 p0 = { acc1[n][0], acc1[n][1] };
    float2 p1 = { acc1[n][2], acc1[n][3] };
    *(float2*)&buf[w][col][lg * 4]     = p0;
    *(float2*)&buf[w][col][lg * 4 + 2] = p1;
  }
  __syncthreads();
  int r = tid >> 4, c0 = (tid & 15) * 8;
  u16x8 o;
#pragma unroll
  for (int i = 0; i < 8; ++i) {
    float s = buf[0][c0 + i][r] + buf[1][c0 + i][r] + buf[2][c0 + i][r] + buf[3][c0 + i][r];
    o[i] = f2bf(s);
  }
  *(u16x8*)(T1bf + (size_t)(row0 + r) * R2 + c0) = o;
}

// ---- 6) out = input + T1 @ D^T, swapped-operand MFMA, no LDS, 2-deep pipeline ----
// grid 2048 blocks x 256 threads; block = 16 rows x 1024 cols; wave = 256 cols (16 tiles).
__global__ __launch_bounds__(256) void k_OUT(const float* __restrict__ input,
                                             const unsigned short* __restrict__ T1bf,
                                             const unsigned short* __restrict__ Dbf,
                                             float* __restrict__ out) {
  const int tid = threadIdx.x, lane = tid & 63, w = tid >> 6;
  const int lr = lane & 15, lg = lane >> 4;
  const int rb = blockIdx.x >> 1, half = blockIdx.x & 1;
  const int row0 = rb * 16;
  const int colbase = half * 1024 + w * 256;

  // T1 fragments (B operand): lane lr -> out-row; reused across all 16 tiles
  bf16x8 bq[4];
  const unsigned short* tp = T1bf + (size_t)(row0 + lr) * R2 + lg * 8;
#pragma unroll
  for (int kt = 0; kt < 4; ++kt) bq[kt] = *(const bf16x8*)(tp + kt * 32);

  const int orow = row0 + lr;
  const float* inp  = input + (size_t)orow * NIN + colbase + lg * 4;
  float*       outp = out   + (size_t)orow * NIN + colbase + lg * 4;
  const unsigned short* dp0 = Dbf + (size_t)(colbase + lr) * R2 + lg * 8;

  bf16x8 xd[4], yd[4];
  float4 xi, yi;

#define O_LOAD(P, T)                                                          \
  do {                                                                        \
    const unsigned short* dpt = dp0 + (size_t)(T) * 16 * R2;                  \
    _Pragma("unroll")                                                         \
    for (int kt = 0; kt < 4; ++kt) P##d[kt] = *(const bf16x8*)(dpt + kt * 32);\
    P##i = *(const float4*)(inp + (T) * 16);                                  \
  } while (0)

#define O_COMP(P, T)                                                          \
  do {                                                                        \
    f32x4 o = {};                                                             \
    _Pragma("unroll")                                                         \
    for (int kt = 0; kt < 4; ++kt)                                            \
      o = __builtin_amdgcn_mfma_f32_16x16x32_bf16(P##d[kt], bq[kt], o, 0, 0, 0); \
    float4 res = { o[0] + P##i.x, o[1] + P##i.y, o[2] + P##i.z, o[3] + P##i.w }; \
    *(float4*)(outp + (T) * 16) = res;                                        \
  } while (0)

  O_LOAD(x, 0);
  for (int t = 0; t < 16; t += 2) {
    O_LOAD(y, t + 1);
    O_COMP(x, t);
    if (t + 2 < 16) O_LOAD(x, t + 2);
    O_COMP(y, t + 1);
  }
}

extern "C" void kernel_launch(void* const* d_in, const int* in_sizes, int n_in,
                              void* d_out, int out_size, void* d_ws, size_t ws_size,
                              hipStream_t stream) {
  const float* input = (const float*)d_in[0];
  const float* U     = (const float*)d_in[1];
  const float* V     = (const float*)d_in[2];
  float* out = (float*)d_out;
  char* ws = (char*)d_ws;

  // workspace layout
  float* mats = (float*)ws;                       // 10 x 128x128 fp32 = 640 KB
  float* G   = mats + 0 * 16384;
  float* G2  = mats + 1 * 16384;
  float* G3  = mats + 2 * 16384;
  float* G4  = mats + 3 * 16384;
  float* G7  = mats + 4 * 16384;
  float* G8  = mats + 5 * 16384;
  float* H12 = mats + 6 * 16384;
  float* H124= mats + 7 * 16384;
  float* H   = mats + 8 * 16384;
  float* G15 = mats + 9 * 16384;
  unsigned short* MbfT = (unsigned short*)(ws + 10 * 65536);              // 512 KB
  unsigned short* Dbf  = (unsigned short*)(ws + 10 * 65536 + 524288);     // 512 KB
  unsigned short* T1bf = (unsigned short*)(ws + 10 * 65536 + 2 * 524288); // 4 MB

  k_convM<<<64, 256, 0, stream>>>(U, V, MbfT, G);
  k_T1<<<1024, 256, 0, stream>>>(input, MbfT, T1bf);
  k_SG<<<512, 256, 0, stream>>>(U, V, G);

  { SOps o = {{ {G,  G,  G2, 0.f, 0.f}, {nullptr,nullptr,nullptr,0.f,0.f}, {nullptr,nullptr,nullptr,0.f,0.f} }};
    k_small<<<64, 256, 0, stream>>>(o); }
  { SOps o = {{ {G2, G2, G4, 0.f, 0.f}, {G2, G, G3, 0.f, 0.f}, {G, G2, H12, 1.f, 1.f} }};
    k_small<<<192, 256, 0, stream>>>(o); }
  { SOps o = {{ {G4, G4, G8, 0.f, 0.f}, {G3, G4, G7, 0.f, 0.f}, {H12, G4, H124, 0.f, 1.f} }};
    k_small<<<192, 256, 0, stream>>>(o); }
  { SOps o = {{ {G7, G8, G15, 0.f, 0.f}, {H124, G8, H, 0.f, 1.f}, {nullptr,nullptr,nullptr,0.f,0.f} }};
    k_small<<<128, 256, 0, stream>>>(o); }

  k_D<<<1024, 256, 0, stream>>>(U, V, H, G15, Dbf);
  k_OUT<<<2048, 256, 0, stream>>>(input, T1bf, Dbf, out);
}

// Round 5
// 140.508 us; speedup vs baseline: 1.5858x; 1.5858x over previous
//
#include <hip/hip_runtime.h>
#include <hip/hip_bf16.h>
#include <cstdint>
#include <cstddef>

// ---- problem constants ----
#define NIN   2048
#define RANK  64
#define R2    128      // 2*RANK
#define NROWS 16384    // 8*2048 flattened batch*seq rows

typedef __bf16 bf16x8 __attribute__((ext_vector_type(8)));
typedef float  f32x4  __attribute__((ext_vector_type(4)));
typedef unsigned short u16x8 __attribute__((ext_vector_type(8)));

__device__ __forceinline__ unsigned short f2bf(float f) {
  union { float f; unsigned u; } x; x.f = f;
  return (unsigned short)((x.u + 0x7fffu + ((x.u >> 16) & 1u)) >> 16);
}

// ---- 1) k_prep: Mf (frag-order) fill + G = J*(M^T M) via K-split atomics ----
// Mf layout: chunk CI = (t*64 + J)*64 + lane  holds  M[t*16 + (lane&15)][J*32 + (lane>>4)*8 + e]
// (M = [U V], column n of M has stride RANK in U/V). 512 blocks; blocks<128 fill Mf.
__global__ void k_prep(const float* __restrict__ U, const float* __restrict__ V,
                       unsigned short* __restrict__ Mf, float* __restrict__ G) {
  int b = blockIdx.x, tid = threadIdx.x;
  if (b < 128) {
    int CI = b * 256 + tid;
    int lane = CI & 63, J = (CI >> 6) & 63, t = CI >> 12;
    int n = t * 16 + (lane & 15);
    int k0 = J * 32 + (lane >> 4) * 8;
    const float* src = (n < RANK) ? (U + n) : (V + (n - RANK));
    u16x8 h;
#pragma unroll
    for (int e = 0; e < 8; ++e) h[e] = f2bf(src[(size_t)(k0 + e) * RANK]);
    *(u16x8*)(Mf + (size_t)CI * 8) = h;
  }
  // G part: 512 blocks = 64 tiles x 8 ksplits
  int tile = b >> 3, ks = b & 7;
  int bi = tile >> 3, bj = tile & 7;
  int ty = tid >> 4, tx = tid & 15;
  int i = bi * 16 + ty, j = bj * 16 + tx;
  const float* Ai = (i < RANK) ? (U + i) : (V + (i - RANK));
  const float* Aj = (j < RANK) ? (U + j) : (V + (j - RANK));
  int k0 = ks * 256;
  float acc = 0.f;
#pragma unroll 8
  for (int k = k0; k < k0 + 256; ++k) acc += Ai[(size_t)k * RANK] * Aj[(size_t)k * RANK];
  if (i < RANK) atomicAdd(&G[(i + RANK) * R2 + j], -acc);
  else          atomicAdd(&G[(i - RANK) * R2 + j],  acc);
}

// ---- 2) generic small 128x128 GEMM: O = (A + a*I)(B + b*I), fp32 ----
struct SOp { const float* A; const float* B; float* O; float a, b; };
struct SOps { SOp op[3]; };
__global__ void k_small(SOps ops) {
  SOp o = ops.op[blockIdx.x >> 6];     // 64 blocks per op
  int t = blockIdx.x & 63;
  int i = (t >> 3) * 16 + (threadIdx.x >> 4);
  int j = (t & 7) * 16 + (threadIdx.x & 15);
  float acc = 0.f;
#pragma unroll 8
  for (int k = 0; k < R2; ++k) {
    float av = o.A[i * R2 + k]; if (k == i) av += o.a;
    float bv = o.B[k * R2 + j]; if (k == j) bv += o.b;
    acc += av * bv;
  }
  o.O[i * R2 + j] = acc;
}

// ---- 3) Df = bf16( M * ((2H - G15) * J) ) in FRAG-ORDER ----
// Df chunk CI = (t*4 + J)*64 + lane holds D[t*16 + (lane&15)][J*32 + (lane>>4)*8 + e]
__global__ void k_D(const float* __restrict__ U, const float* __restrict__ V,
                    const float* __restrict__ H, const float* __restrict__ G15,
                    unsigned short* __restrict__ Df) {
  int idx = blockIdx.x * 256 + threadIdx.x;  // i*128 + j, i < 2048
  int i = idx >> 7, j = idx & 127;
  int jj = (j < RANK) ? (j + RANK) : (j - RANK);
  float sgn = (j < RANK) ? -1.f : 1.f;
  float acc = 0.f;
#pragma unroll 8
  for (int k = 0; k < R2; ++k) {
    float m = (k < RANK) ? U[(size_t)i * RANK + k] : V[(size_t)i * RANK + (k - RANK)];
    float t = 2.f * H[k * R2 + jj] - G15[k * R2 + jj];
    acc += m * (sgn * t);
  }
  int t_ = i >> 4, lr = i & 15;
  int J = j >> 5, lg = (j >> 3) & 3, e = j & 7;
  size_t CI = (size_t)(t_ * 4 + J) * 64 + lg * 16 + lr;
  Df[CI * 8 + e] = f2bf(acc);
}

// ---- 4) k_T1: T1bf = bf16(input @ M). 512 blocks x 256 thr; block = 32 rows.
// Wave w owns K-range [w*512,(w+1)*512), 4 K-steps of 128. Input staged through
// per-wave swizzled LDS (coalesced loads); M frags loaded contiguous from Mf.
__global__ __launch_bounds__(256) void k_T1(const float* __restrict__ input,
                                            const unsigned short* __restrict__ Mf,
                                            unsigned short* __restrict__ T1bf) {
  __shared__ __align__(16) unsigned char lds[73728];  // abuf[w] 8KB x4 (compute), then rbuf[4][128][36] f32
  const int tid = threadIdx.x, lane = tid & 63, w = tid >> 6;
  const int lr = lane & 15, lg = lane >> 4;
  const int row0 = blockIdx.x * 32;
  unsigned char* abuf = lds + w * 8192;
  float* rbuf = (float*)lds;

  f32x4 acc[2][8] = {};
  const float* gbase = input + (size_t)row0 * NIN + w * 512;
  const int Jbase = w * 16;

  float4 s0[8], s1[8];
  bf16x8 bx[8], by[8];

#define T1_SLOAD(KT)                                                          \
  _Pragma("unroll") for (int p = 0; p < 8; ++p) {                             \
    int id = p * 64 + lane; int r = id >> 4, C = id & 15;                     \
    const float* g = gbase + (size_t)r * NIN + (KT) * 128 + C * 8;            \
    s0[p] = *(const float4*)g; s1[p] = *(const float4*)(g + 4);               \
  }
#define T1_SWRITE()                                                           \
  _Pragma("unroll") for (int p = 0; p < 8; ++p) {                             \
    int id = p * 64 + lane; int r = id >> 4, C = id & 15;                     \
    u16x8 h;                                                                  \
    h[0] = f2bf(s0[p].x); h[1] = f2bf(s0[p].y);                               \
    h[2] = f2bf(s0[p].z); h[3] = f2bf(s0[p].w);                               \
    h[4] = f2bf(s1[p].x); h[5] = f2bf(s1[p].y);                               \
    h[6] = f2bf(s1[p].z); h[7] = f2bf(s1[p].w);                               \
    *(u16x8*)(abuf + r * 256 + ((C ^ (r & 7)) << 4)) = h;                     \
  }
#define T1_BLOAD(P, S)                                                        \
  _Pragma("unroll") for (int t = 0; t < 8; ++t)                               \
    P[t] = *(const bf16x8*)(Mf + ((size_t)(t * 64 + Jbase + (S)) * 64 + lane) * 8);

  // prologue
  T1_SLOAD(0);
  T1_SWRITE();
  T1_BLOAD(bx, 0);

#pragma unroll
  for (int s = 0; s < 16; ++s) {
    const int kt = s >> 2, j = s & 3;
    if (j == 0 && kt < 3) { T1_SLOAD(kt + 1); }       // next K-step input in flight
    // A frags for (kt, j)
    bf16x8 a0, a1;
    {
      int C = j * 4 + lg;
      a0 = *(const bf16x8*)(abuf + lr * 256 + ((C ^ (lr & 7)) << 4));
      a1 = *(const bf16x8*)(abuf + (16 + lr) * 256 + ((C ^ ((16 + lr) & 7)) << 4));
    }
    if (s < 15) { if (s & 1) { T1_BLOAD(bx, s + 1); } else { T1_BLOAD(by, s + 1); } }
#pragma unroll
    for (int t = 0; t < 8; ++t) {
      bf16x8 bcur = (s & 1) ? by[t] : bx[t];
      acc[0][t] = __builtin_amdgcn_mfma_f32_16x16x32_bf16(a0, bcur, acc[0][t], 0, 0, 0);
      acc[1][t] = __builtin_amdgcn_mfma_f32_16x16x32_bf16(a1, bcur, acc[1][t], 0, 0, 0);
    }
    if (j == 3 && kt < 3) { T1_SWRITE(); }            // stage next K-step (after this kt's reads)
  }

  __syncthreads();   // all waves done with abuf before rbuf overlay
  // partials -> rbuf[w][col][row]: C layout col = t*16+lr, row = m*16+lg*4+e
#pragma unroll
  for (int m = 0; m < 2; ++m)
#pragma unroll
    for (int t = 0; t < 8; ++t) {
      int col = t * 16 + lr, row = m * 16 + lg * 4;
      *(f32x4*)&rbuf[((size_t)w * 128 + col) * 36 + row] = acc[m][t];
    }
  __syncthreads();
  // reduce: thread (r = tid&31, cg = tid>>5) handles row r, cols cg*16..+16
  {
    int r = tid & 31, cg = tid >> 5;
    u16x8 o1, o2;
#pragma unroll
    for (int i = 0; i < 16; ++i) {
      int col = cg * 16 + i;
      float s = rbuf[(size_t)col * 36 + r]
              + rbuf[((size_t)128 + col) * 36 + r]
              + rbuf[((size_t)256 + col) * 36 + r]
              + rbuf[((size_t)384 + col) * 36 + r];
      if (i < 8) o1[i] = f2bf(s); else o2[i - 8] = f2bf(s);
    }
    unsigned short* dst = T1bf + (size_t)(row0 + r) * R2 + cg * 16;
    *(u16x8*)dst = o1;
    *(u16x8*)(dst + 8) = o2;
  }
}

// ---- 5) k_OUT: out = input + T1 @ D^T. 512 blocks x 256 thr; block = 32 rows x 2048 cols.
// Wave w owns cols [w*512,(w+1)*512). T1 frags persistent in regs; Df streamed coalesced;
// epilogue transposed through per-wave LDS so input/out accesses are contiguous. No barriers.
__global__ __launch_bounds__(256) void k_OUT(const float* __restrict__ input,
                                             const unsigned short* __restrict__ T1bf,
                                             const unsigned short* __restrict__ Df,
                                             float* __restrict__ out) {
  __shared__ float obuf[4][32][132];   // per-wave [32 rows][128 cols + pad4]
  const int tid = threadIdx.x, lane = tid & 63, w = tid >> 6;
  const int lr = lane & 15, lg = lane >> 4;
  const int row0 = blockIdx.x * 32;

  // persistent T1 B-frags: bq[R][J] — lane holds T1[row0+R*16+lr][J*32+lg*8..+8]
  bf16x8 bq[2][4];
#pragma unroll
  for (int R = 0; R < 2; ++R)
#pragma unroll
    for (int J = 0; J < 4; ++J)
      bq[R][J] = *(const bf16x8*)(T1bf + (size_t)(row0 + R * 16 + lr) * R2 + J * 32 + lg * 8);

  bf16x8 xd[4], yd[4];
#define O_DLOAD(P, TTI)                                                       \
  _Pragma("unroll") for (int J = 0; J < 4; ++J)                               \
    P[J] = *(const bf16x8*)(Df + ((size_t)((w * 32 + (TTI)) * 4 + J) * 64 + lane) * 8);

  O_DLOAD(xd, 0);
#pragma unroll
  for (int g = 0; g < 4; ++g) {
#pragma unroll
    for (int tt = 0; tt < 8; ++tt) {
      const int tti = g * 8 + tt;
      if (tti < 31) { if (tti & 1) { O_DLOAD(xd, tti + 1); } else { O_DLOAD(yd, tti + 1); } }
#pragma unroll
      for (int R = 0; R < 2; ++R) {
        f32x4 o = {};
#pragma unroll
        for (int J = 0; J < 4; ++J) {
          bf16x8 d = (tti & 1) ? yd[J] : xd[J];
          o = __builtin_amdgcn_mfma_f32_16x16x32_bf16(d, bq[R][J], o, 0, 0, 0);
        }
        // C layout: out-row = R*16+lr, out-col = tt*16 + lg*4 + e
        *(f32x4*)&obuf[w][R * 16 + lr][tt * 16 + lg * 4] = o;
      }
    }
    // epilogue for this 128-col group: contiguous input read + out write
#pragma unroll
    for (int c = 0; c < 16; ++c) {
      int id = c * 64 + lane;
      int r = id >> 5, cc = id & 31;
      f32x4 v = *(const f32x4*)&obuf[w][r][cc * 4];
      int grow = row0 + r, gcol = w * 512 + g * 128 + cc * 4;
      float4 inv = *(const float4*)(input + (size_t)grow * NIN + gcol);
      float4 res = { v[0] + inv.x, v[1] + inv.y, v[2] + inv.z, v[3] + inv.w };
      *(float4*)(out + (size_t)grow * NIN + gcol) = res;
    }
  }
}

extern "C" void kernel_launch(void* const* d_in, const int* in_sizes, int n_in,
                              void* d_out, int out_size, void* d_ws, size_t ws_size,
                              hipStream_t stream) {
  const float* input = (const float*)d_in[0];
  const float* U     = (const float*)d_in[1];
  const float* V     = (const float*)d_in[2];
  float* out = (float*)d_out;
  char* ws = (char*)d_ws;

  // workspace layout
  float* mats = (float*)ws;                       // 10 x 128x128 fp32 = 640 KB
  float* G   = mats + 0 * 16384;
  float* G2  = mats + 1 * 16384;
  float* G3  = mats + 2 * 16384;
  float* G4  = mats + 3 * 16384;
  float* G7  = mats + 4 * 16384;
  float* G8  = mats + 5 * 16384;
  float* H12 = mats + 6 * 16384;
  float* H124= mats + 7 * 16384;
  float* H   = mats + 8 * 16384;
  float* G15 = mats + 9 * 16384;
  unsigned short* Mf   = (unsigned short*)(ws + 10 * 65536);              // 512 KB frag-order M
  unsigned short* Df   = (unsigned short*)(ws + 10 * 65536 + 524288);     // 512 KB frag-order D
  unsigned short* T1bf = (unsigned short*)(ws + 10 * 65536 + 2 * 524288); // 4 MB

  hipMemsetAsync(G, 0, R2 * R2 * sizeof(float), stream);
  k_prep<<<512, 256, 0, stream>>>(U, V, Mf, G);
  k_T1<<<512, 256, 0, stream>>>(input, Mf, T1bf);

  { SOps o = {{ {G,  G,  G2, 0.f, 0.f}, {nullptr,nullptr,nullptr,0.f,0.f}, {nullptr,nullptr,nullptr,0.f,0.f} }};
    k_small<<<64, 256, 0, stream>>>(o); }
  { SOps o = {{ {G2, G2, G4, 0.f, 0.f}, {G2, G, G3, 0.f, 0.f}, {G, G2, H12, 1.f, 1.f} }};
    k_small<<<192, 256, 0, stream>>>(o); }
  { SOps o = {{ {G4, G4, G8, 0.f, 0.f}, {G3, G4, G7, 0.f, 0.f}, {H12, G4, H124, 0.f, 1.f} }};
    k_small<<<192, 256, 0, stream>>>(o); }
  { SOps o = {{ {G7, G8, G15, 0.f, 0.f}, {H124, G8, H, 0.f, 1.f}, {nullptr,nullptr,nullptr,0.f,0.f} }};
    k_small<<<128, 256, 0, stream>>>(o); }

  k_D<<<1024, 256, 0, stream>>>(U, V, H, G15, Df);
  k_OUT<<<512, 256, 0, stream>>>(input, T1bf, Df, out);
}